// Round 1
// baseline (402.182 us; speedup 1.0000x reference)
//
#include <hip/hip_runtime.h>
#include <hip/hip_bf16.h>

// CouplingSplineLayer fused kernel for MI355X (gfx950).
// GEMM1(8->256)+relu -> GEMM2(256->256)+relu -> GEMM3(256->184) -> RQ spline.
// bf16 MFMA (16x16x32), weights pre-swizzled into B-fragment layout in d_ws.

typedef __bf16 bf16x8 __attribute__((ext_vector_type(8)));
typedef float  f32x4  __attribute__((ext_vector_type(4)));

#define MFMA16(a,b,c) __builtin_amdgcn_mfma_f32_16x16x32_bf16((a),(b),(c),0,0,0)

// swizzled weight regions (bf16 element offsets in d_ws)
#define SW_W1_OFF 8192      // W0 region: 1 kb * 16 nt * 512 = 8192
#define SW_WO_OFF 73728     // W1 region: 8 kb * 16 nt * 512 = 65536
#define SW_TOTAL  122880    // Wout region: 8 kb * 12 nt * 512 = 49152

__global__ void prep_kernel(const float* __restrict__ W0,
                            const float* __restrict__ W1,
                            const float* __restrict__ Wout,
                            __bf16* __restrict__ sw)
{
  int i = blockIdx.x * 256 + threadIdx.x;
  if (i >= SW_TOTAL) return;
  const float* src; int K, N, NT, li;
  if (i < SW_W1_OFF)      { src = W0;   K = 8;   N = 256; NT = 16; li = i; }
  else if (i < SW_WO_OFF) { src = W1;   K = 256; N = 256; NT = 16; li = i - SW_W1_OFF; }
  else                    { src = Wout; K = 256; N = 184; NT = 12; li = i - SW_WO_OFF; }
  int j    = li & 7;
  int l    = (li >> 3) & 63;
  int rest = li >> 9;
  int nt   = rest % NT;
  int kb   = rest / NT;
  int k = kb * 32 + ((l >> 4) << 3) + j;   // B-frag: k = quad*8 + j
  int n = nt * 16 + (l & 15);              //         n = lane&15
  float v = (k < K && n < N) ? src[k * N + n] : 0.0f;
  sw[i] = (__bf16)v;
}

__device__ __forceinline__ float sel8(const float a[8], int idx){
  float v = a[0];
  #pragma unroll
  for (int i = 1; i < 8; i++) v = (idx == i) ? a[i] : v;
  return v;
}
__device__ __forceinline__ float sel9(const float a[9], int idx){
  float v = a[0];
  #pragma unroll
  for (int i = 1; i < 9; i++) v = (idx == i) ? a[i] : v;
  return v;
}

__global__ __launch_bounds__(256, 2)
void fused_kernel(const float* __restrict__ x,
                  const float* __restrict__ b0v,
                  const float* __restrict__ b1v,
                  const float* __restrict__ boutv,
                  const __bf16* __restrict__ sw,
                  float* __restrict__ out,
                  int nrows)
{
  // LDS: [0,32768) h1 (64x256 bf16, XOR-swizzled) later aliased by raw (64x188 bf16)
  //      [32768,65536) h2 (64x256 bf16, XOR-swizzled) later aliased by ldet (512 f32)
  __shared__ __align__(16) unsigned char smem_raw[65536];
  __bf16* h1   = (__bf16*)smem_raw;
  __bf16* h2   = (__bf16*)(smem_raw + 32768);
  __bf16* rawb = (__bf16*)smem_raw;
  float*  ldet = (float*)(smem_raw + 32768);

  const int tid  = threadIdx.x;
  const int wave = tid >> 6;
  const int lane = tid & 63;
  const int quad = lane >> 4;
  const int l16  = lane & 15;
  const int row0 = blockIdx.x * 64;

  const __bf16* swW1 = sw + SW_W1_OFF;
  const __bf16* swWo = sw + SW_WO_OFF;

  const f32x4 z4 = {0.f, 0.f, 0.f, 0.f};

  // ---------------- GEMM1: h1 = relu(x2 @ W0 + b0) ----------------
  {
    bf16x8 a1[4];
    #pragma unroll
    for (int mt = 0; mt < 4; mt++){
      // A-frag: m = lane&15, k = quad*8+j. Only k<8 matters (B zero-padded past 8),
      // so every quad just loads its row's x2 (same addr per quad -> L1 broadcast).
      const float* xp = x + (long)(row0 + mt*16 + l16) * 16 + 8;
      float4 u = *(const float4*)xp;
      float4 v = *(const float4*)(xp + 4);
      bf16x8 a;
      a[0]=(__bf16)u.x; a[1]=(__bf16)u.y; a[2]=(__bf16)u.z; a[3]=(__bf16)u.w;
      a[4]=(__bf16)v.x; a[5]=(__bf16)v.y; a[6]=(__bf16)v.z; a[7]=(__bf16)v.w;
      a1[mt] = a;
    }
    f32x4 acc[4][4];
    #pragma unroll
    for (int mt=0;mt<4;mt++)
      #pragma unroll
      for (int nt=0;nt<4;nt++) acc[mt][nt] = z4;
    #pragma unroll
    for (int nt=0;nt<4;nt++){
      bf16x8 b = *(const bf16x8*)(sw + ((wave*4 + nt)*64 + lane)*8);
      #pragma unroll
      for (int mt=0;mt<4;mt++) acc[mt][nt] = MFMA16(a1[mt], b, acc[mt][nt]);
    }
    #pragma unroll
    for (int nt=0;nt<4;nt++){
      int col = wave*64 + nt*16 + l16;
      float bias = b0v[col];
      #pragma unroll
      for (int mt=0;mt<4;mt++)
        #pragma unroll
        for (int r=0;r<4;r++){
          int row = mt*16 + quad*4 + r;       // C/D: row = quad*4+reg, col = lane&15
          float v = fmaxf(acc[mt][nt][r] + bias, 0.f);
          int ch = (col >> 3) ^ (row & 7);    // 16B-chunk XOR swizzle
          h1[row*256 + ch*8 + (col & 7)] = (__bf16)v;
        }
    }
  }
  __syncthreads();

  // ---------------- GEMM2: h2 = relu(h1 @ W1 + b1) ----------------
  {
    f32x4 acc[4][4];
    #pragma unroll
    for (int mt=0;mt<4;mt++)
      #pragma unroll
      for (int nt=0;nt<4;nt++) acc[mt][nt] = z4;
    #pragma unroll
    for (int kb=0;kb<8;kb++){
      bf16x8 af[4];
      #pragma unroll
      for (int mt=0;mt<4;mt++){
        int row = mt*16 + l16;
        int ch = (kb*4 + quad) ^ (row & 7);
        af[mt] = *(const bf16x8*)(h1 + row*256 + ch*8);
      }
      bf16x8 bfr[4];
      #pragma unroll
      for (int nt=0;nt<4;nt++)
        bfr[nt] = *(const bf16x8*)(swW1 + ((kb*16 + wave*4 + nt)*64 + lane)*8);
      #pragma unroll
      for (int mt=0;mt<4;mt++)
        #pragma unroll
        for (int nt=0;nt<4;nt++)
          acc[mt][nt] = MFMA16(af[mt], bfr[nt], acc[mt][nt]);
    }
    #pragma unroll
    for (int nt=0;nt<4;nt++){
      int col = wave*64 + nt*16 + l16;
      float bias = b1v[col];
      #pragma unroll
      for (int mt=0;mt<4;mt++)
        #pragma unroll
        for (int r=0;r<4;r++){
          int row = mt*16 + quad*4 + r;
          float v = fmaxf(acc[mt][nt][r] + bias, 0.f);
          int ch = (col >> 3) ^ (row & 7);
          h2[row*256 + ch*8 + (col & 7)] = (__bf16)v;
        }
    }
  }
  __syncthreads();

  // ---------------- GEMM3: raw = h2 @ Wout + bout ----------------
  {
    f32x4 acc[4][3];
    #pragma unroll
    for (int mt=0;mt<4;mt++)
      #pragma unroll
      for (int nt=0;nt<3;nt++) acc[mt][nt] = z4;
    #pragma unroll
    for (int kb=0;kb<8;kb++){
      bf16x8 af[4];
      #pragma unroll
      for (int mt=0;mt<4;mt++){
        int row = mt*16 + l16;
        int ch = (kb*4 + quad) ^ (row & 7);
        af[mt] = *(const bf16x8*)(h2 + row*256 + ch*8);
      }
      bf16x8 bfr[3];
      #pragma unroll
      for (int nt=0;nt<3;nt++)
        bfr[nt] = *(const bf16x8*)(swWo + ((kb*12 + wave*3 + nt)*64 + lane)*8);
      #pragma unroll
      for (int mt=0;mt<4;mt++)
        #pragma unroll
        for (int nt=0;nt<3;nt++)
          acc[mt][nt] = MFMA16(af[mt], bfr[nt], acc[mt][nt]);
    }
    #pragma unroll
    for (int nt=0;nt<3;nt++){
      int col = wave*48 + nt*16 + l16;
      float bias = (col < 184) ? boutv[col] : 0.f;
      #pragma unroll
      for (int mt=0;mt<4;mt++)
        #pragma unroll
        for (int r=0;r<4;r++){
          int row = mt*16 + quad*4 + r;
          if (col < 184)
            rawb[row*188 + col] = (__bf16)(acc[mt][nt][r] + bias);
        }
    }
  }
  __syncthreads();

  // ---------------- RQ spline epilogue ----------------
  // 512 (row, transform) tasks; 2 per thread.
  #pragma unroll
  for (int pp = 0; pp < 2; pp++){
    int p   = tid + pp*256;
    int row = p >> 3;
    int t   = p & 7;
    int gr  = row0 + row;
    const __bf16* rr = rawb + row*188 + t*23;
    float xv = x[(long)gr*16 + t];
    out[(long)gr*16 + 8 + t] = x[(long)gr*16 + 8 + t];  // x2 passthrough

    float w8[8], h8[8];
    {
      float e[8]; float m = -1e30f;
      #pragma unroll
      for (int i=0;i<8;i++){ e[i] = (float)rr[i]; m = fmaxf(m, e[i]); }
      float s = 0.f;
      #pragma unroll
      for (int i=0;i<8;i++){ e[i] = __expf(e[i]-m); s += e[i]; }
      float inv = 1.0f / s;
      #pragma unroll
      for (int i=0;i<8;i++) w8[i] = 2.0f*(1e-4f + 0.9992f * e[i] * inv);
    }
    {
      float e[8]; float m = -1e30f;
      #pragma unroll
      for (int i=0;i<8;i++){ e[i] = (float)rr[8+i]; m = fmaxf(m, e[i]); }
      float s = 0.f;
      #pragma unroll
      for (int i=0;i<8;i++){ e[i] = __expf(e[i]-m); s += e[i]; }
      float inv = 1.0f / s;
      #pragma unroll
      for (int i=0;i<8;i++) h8[i] = 2.0f*(1e-4f + 0.9992f * e[i] * inv);
    }
    float d9[9];
    d9[0] = 1.f; d9[8] = 1.f;
    #pragma unroll
    for (int i=0;i<7;i++){
      float z = (float)rr[16+i] + 0.54116666f;   // log(exp(1-MIN_D)-1)
      float sp = (z > 0.f) ? (z + log1pf(__expf(-z))) : log1pf(__expf(z));
      d9[i+1] = sp + 1e-4f;
    }
    float cw[9], chh[9];
    cw[0] = -1.f; chh[0] = -1.f;
    float aw = -1.f, ah = -1.f;
    #pragma unroll
    for (int i=0;i<8;i++){ aw += w8[i]; cw[i+1] = aw; ah += h8[i]; chh[i+1] = ah; }

    bool msk = (xv <= -0.999f) || (xv >= 0.999f);
    float xin = msk ? 0.f : xv;
    int idx = 0;
    #pragma unroll
    for (int i=1;i<9;i++) idx += (cw[i] <= xin) ? 1 : 0;
    idx = (idx > 7) ? 7 : idx;

    float xk  = sel9(cw,  idx);
    float yk  = sel9(chh, idx);
    float wk  = sel8(w8,  idx);
    float hk  = sel8(h8,  idx);
    float dk  = sel9(d9,  idx);
    float dk1 = sel9(d9,  idx+1);

    float sk  = hk / wk;
    float eps = (xin - xk) / wk;
    float om  = 1.f - eps;
    float et  = eps * om;
    float e2  = eps * eps;
    float beta  = sk + (dk1 + dk - 2.f*sk) * et;
    float alpha = hk * (sk*e2 + dk*et);
    float yv  = msk ? xv : (yk + alpha / beta);
    float num = dk1*e2 + 2.f*sk*et + dk*om*om;
    float ld  = msk ? 0.f : (2.f*__logf(sk) + __logf(num) - 2.f*__logf(beta));

    out[(long)gr*16 + t] = yv;
    ldet[p] = ld;
  }
  __syncthreads();

  if (tid < 64){
    float s = 0.f;
    #pragma unroll
    for (int t=0;t<8;t++) s += ldet[tid*8 + t];
    out[(long)nrows*16 + row0 + tid] = s;
  }
}

extern "C" void kernel_launch(void* const* d_in, const int* in_sizes, int n_in,
                              void* d_out, int out_size, void* d_ws, size_t ws_size,
                              hipStream_t stream)
{
  const float* x    = (const float*)d_in[0];
  const float* W0   = (const float*)d_in[1];
  const float* b0   = (const float*)d_in[2];
  const float* W1   = (const float*)d_in[3];
  const float* b1   = (const float*)d_in[4];
  const float* Wout = (const float*)d_in[5];
  const float* bout = (const float*)d_in[6];
  float* out = (float*)d_out;
  __bf16* sw = (__bf16*)d_ws;

  int nrows = in_sizes[0] / 16;          // 524288
  int ntiles = nrows / 64;               // 8192

  prep_kernel<<<(SW_TOTAL + 255)/256, 256, 0, stream>>>(W0, W1, Wout, sw);
  fused_kernel<<<ntiles, 256, 0, stream>>>(x, b0, b1, bout, sw, out, nrows);
}

// Round 2
// 271.387 us; speedup vs baseline: 1.4819x; 1.4819x over previous
//
#include <hip/hip_runtime.h>
#include <hip/hip_bf16.h>

// CouplingSplineLayer fused kernel for MI355X (gfx950), round 2.
// GEMM1(8->256)+relu -> GEMM2(256->256)+relu -> GEMM3(256->184) -> RQ spline.
// bf16 MFMA 16x16x32; weights pre-swizzled to B-fragment layout in d_ws.
// R2: scratch-free spline (cndmask scan), 512-thr blocks (16 waves/CU),
//     padded LDS strides instead of XOR swizzle, cheap transcendentals.

typedef __bf16 bf16x8 __attribute__((ext_vector_type(8)));
typedef float  f32x4  __attribute__((ext_vector_type(4)));

#define MFMA16(a,b,c) __builtin_amdgcn_mfma_f32_16x16x32_bf16((a),(b),(c),0,0,0)

// swizzled weight regions (bf16 element offsets in d_ws)
#define SW_W1_OFF 8192      // W0: 1 kb * 16 nt * 512
#define SW_WO_OFF 73728     // W1: 8 kb * 16 nt * 512
#define SW_TOTAL  122880    // Wout: 8 kb * 12 nt * 512

#define HSTRIDE 264         // h1/h2 row stride in bf16 (264*2B: bank rot = row*4)
#define RSTRIDE 200         // raw row stride in bf16; t-slot = t*24 (+j), 48B aligned

__global__ void prep_kernel(const float* __restrict__ W0,
                            const float* __restrict__ W1,
                            const float* __restrict__ Wout,
                            __bf16* __restrict__ sw)
{
  int i = blockIdx.x * 256 + threadIdx.x;
  if (i >= SW_TOTAL) return;
  const float* src; int K, N, NT, li;
  if (i < SW_W1_OFF)      { src = W0;   K = 8;   N = 256; NT = 16; li = i; }
  else if (i < SW_WO_OFF) { src = W1;   K = 256; N = 256; NT = 16; li = i - SW_W1_OFF; }
  else                    { src = Wout; K = 256; N = 184; NT = 12; li = i - SW_WO_OFF; }
  int j    = li & 7;
  int l    = (li >> 3) & 63;
  int rest = li >> 9;
  int nt   = rest % NT;
  int kb   = rest / NT;
  int k = kb * 32 + ((l >> 4) << 3) + j;   // B-frag: k = quad*8 + j
  int n = nt * 16 + (l & 15);              //         n = lane&15
  float v = (k < K && n < N) ? src[k * N + n] : 0.0f;
  sw[i] = (__bf16)v;
}

__global__ __launch_bounds__(512, 4)
void fused_kernel(const float* __restrict__ x,
                  const float* __restrict__ b0v,
                  const float* __restrict__ b1v,
                  const float* __restrict__ boutv,
                  const __bf16* __restrict__ sw,
                  float* __restrict__ out,
                  int nrows)
{
  // [0, 33792)      h1 (64 x HSTRIDE bf16), later aliased by raw (64 x RSTRIDE bf16)
  // [33792, 67584)  h2 (64 x HSTRIDE bf16), later aliased by ldet (512 f32)
  __shared__ __align__(16) unsigned char smem[2 * 64 * HSTRIDE * 2];
  __bf16* h1   = (__bf16*)smem;
  __bf16* h2   = (__bf16*)(smem + 64 * HSTRIDE * 2);
  __bf16* rawb = h1;
  float*  ldet = (float*)h2;

  const int tid  = threadIdx.x;
  const int wave = tid >> 6;
  const int lane = tid & 63;
  const int quad = lane >> 4;
  const int l16  = lane & 15;
  const int row0 = blockIdx.x * 64;

  const __bf16* swW1 = sw + SW_W1_OFF;
  const __bf16* swWo = sw + SW_WO_OFF;

  const f32x4 z4 = {0.f, 0.f, 0.f, 0.f};

  // ---------------- GEMM1: h1 = relu(x2 @ W0 + b0) ----------------
  {
    bf16x8 a1[4];
    #pragma unroll
    for (int mt = 0; mt < 4; mt++){
      // A-frag: m=lane&15, k=quad*8+j; only k<8 nonzero (B zero-padded), so all
      // quads load the same row's x2 (L1 broadcast).
      const float* xp = x + (long)(row0 + mt*16 + l16) * 16 + 8;
      float4 u = *(const float4*)xp;
      float4 v = *(const float4*)(xp + 4);
      bf16x8 a;
      a[0]=(__bf16)u.x; a[1]=(__bf16)u.y; a[2]=(__bf16)u.z; a[3]=(__bf16)u.w;
      a[4]=(__bf16)v.x; a[5]=(__bf16)v.y; a[6]=(__bf16)v.z; a[7]=(__bf16)v.w;
      a1[mt] = a;
    }
    f32x4 acc[4][2];
    #pragma unroll
    for (int mt=0;mt<4;mt++){ acc[mt][0]=z4; acc[mt][1]=z4; }
    #pragma unroll
    for (int nt=0;nt<2;nt++){
      int ntg = wave*2 + nt;
      bf16x8 b = *(const bf16x8*)(sw + (ntg*64 + lane)*8);
      #pragma unroll
      for (int mt=0;mt<4;mt++) acc[mt][nt] = MFMA16(a1[mt], b, acc[mt][nt]);
    }
    #pragma unroll
    for (int nt=0;nt<2;nt++){
      int col = wave*32 + nt*16 + l16;
      float bias = b0v[col];
      #pragma unroll
      for (int mt=0;mt<4;mt++)
        #pragma unroll
        for (int r=0;r<4;r++){
          int row = mt*16 + quad*4 + r;          // C/D: row=quad*4+reg, col=lane&15
          h1[row*HSTRIDE + col] = (__bf16)fmaxf(acc[mt][nt][r] + bias, 0.f);
        }
    }
  }
  __syncthreads();

  // ---------------- GEMM2: h2 = relu(h1 @ W1 + b1) ----------------
  {
    f32x4 acc[4][2];
    #pragma unroll
    for (int mt=0;mt<4;mt++){ acc[mt][0]=z4; acc[mt][1]=z4; }
    #pragma unroll
    for (int kb=0;kb<8;kb++){
      bf16x8 af[4];
      #pragma unroll
      for (int mt=0;mt<4;mt++){
        int row = mt*16 + l16;
        af[mt] = *(const bf16x8*)(h1 + row*HSTRIDE + kb*32 + quad*8);
      }
      #pragma unroll
      for (int nt=0;nt<2;nt++){
        int ntg = wave*2 + nt;
        bf16x8 b = *(const bf16x8*)(swW1 + ((kb*16 + ntg)*64 + lane)*8);
        #pragma unroll
        for (int mt=0;mt<4;mt++) acc[mt][nt] = MFMA16(af[mt], b, acc[mt][nt]);
      }
    }
    #pragma unroll
    for (int nt=0;nt<2;nt++){
      int col = wave*32 + nt*16 + l16;
      float bias = b1v[col];
      #pragma unroll
      for (int mt=0;mt<4;mt++)
        #pragma unroll
        for (int r=0;r<4;r++){
          int row = mt*16 + quad*4 + r;
          h2[row*HSTRIDE + col] = (__bf16)fmaxf(acc[mt][nt][r] + bias, 0.f);
        }
    }
  }
  __syncthreads();

  // ---------------- GEMM3: raw = h2 @ Wout + bout (into spline-friendly LDS) ----
  {
    f32x4 acc[4][2];
    #pragma unroll
    for (int mt=0;mt<4;mt++){ acc[mt][0]=z4; acc[mt][1]=z4; }
    const bool has2 = (wave < 4);
    #pragma unroll
    for (int kb=0;kb<8;kb++){
      bf16x8 af[4];
      #pragma unroll
      for (int mt=0;mt<4;mt++){
        int row = mt*16 + l16;
        af[mt] = *(const bf16x8*)(h2 + row*HSTRIDE + kb*32 + quad*8);
      }
      bf16x8 b0 = *(const bf16x8*)(swWo + ((kb*12 + wave)*64 + lane)*8);
      #pragma unroll
      for (int mt=0;mt<4;mt++) acc[mt][0] = MFMA16(af[mt], b0, acc[mt][0]);
      if (has2){
        bf16x8 b1 = *(const bf16x8*)(swWo + ((kb*12 + wave + 8)*64 + lane)*8);
        #pragma unroll
        for (int mt=0;mt<4;mt++) acc[mt][1] = MFMA16(af[mt], b1, acc[mt][1]);
      }
    }
    #pragma unroll
    for (int s=0;s<2;s++){
      if (s == 1 && !has2) break;
      int ntg = s ? (wave + 8) : wave;
      int col = ntg*16 + l16;
      if (col < 184){
        int t = (col * 713) >> 14;              // t = col / 23 for col<184
        float bias = boutv[col];
        #pragma unroll
        for (int mt=0;mt<4;mt++)
          #pragma unroll
          for (int r=0;r<4;r++){
            int row = mt*16 + quad*4 + r;
            rawb[row*RSTRIDE + col + t] = (__bf16)(acc[mt][s][r] + bias);
          }
      }
    }
  }
  __syncthreads();

  // ---------------- RQ spline epilogue: 512 tasks, 1/thread, scratch-free ------
  {
    int row = tid >> 3;
    int t   = tid & 7;
    long gr = row0 + row;
    float xv = x[gr*16 + t];
    out[gr*16 + 8 + t] = x[gr*16 + 8 + t];      // x2 passthrough

    const __bf16* rr = rawb + row*RSTRIDE + t*24;
    bf16x8 v0 = *(const bf16x8*)(rr);
    bf16x8 v1 = *(const bf16x8*)(rr + 8);
    bf16x8 v2 = *(const bf16x8*)(rr + 16);

    // softmax sums (no max-sub: |raw| << 1, overflow impossible)
    float ew[8], eh[8];
    float sw_ = 0.f, sh_ = 0.f;
    #pragma unroll
    for (int i=0;i<8;i++){ ew[i] = __expf((float)v0[i]); sw_ += ew[i]; }
    #pragma unroll
    for (int i=0;i<8;i++){ eh[i] = __expf((float)v1[i]); sh_ += eh[i]; }
    float cw = 1.9984f * __builtin_amdgcn_rcpf(sw_);
    float ch = 1.9984f * __builtin_amdgcn_rcpf(sh_);

    // derivatives d[0..8], d0=d8=1, softplus(raw_d + const) + MIN_D
    float d[9];
    d[0] = 1.f; d[8] = 1.f;
    #pragma unroll
    for (int i=0;i<7;i++){
      float z = (float)v2[i] + 0.54116666f;     // log(exp(1-MIN_D)-1)
      d[i+1] = fmaxf(z, 0.f) + __logf(1.f + __expf(-fabsf(z))) + 1e-4f;
    }

    bool msk = (xv <= -0.999f) || (xv >= 0.999f);
    float xin = msk ? 0.f : xv;

    // running cndmask scan: pick last bin whose left edge <= xin
    float w_i = fmaf(ew[0], cw, 2e-4f);
    float h_i = fmaf(eh[0], ch, 2e-4f);
    float edge = -1.f + w_i, cy = -1.f + h_i;
    float xk = -1.f, yk = -1.f, wk = w_i, hk = h_i, dk = d[0], dk1 = d[1];
    #pragma unroll
    for (int i=1;i<8;i++){
      w_i = fmaf(ew[i], cw, 2e-4f);
      h_i = fmaf(eh[i], ch, 2e-4f);
      bool le = (edge <= xin);
      xk  = le ? edge : xk;
      yk  = le ? cy   : yk;
      wk  = le ? w_i  : wk;
      hk  = le ? h_i  : hk;
      dk  = le ? d[i] : dk;
      dk1 = le ? d[i+1] : dk1;
      edge += w_i; cy += h_i;
    }

    float rwk = __builtin_amdgcn_rcpf(wk);
    float sk  = hk * rwk;
    float eps = (xin - xk) * rwk;
    float om  = 1.f - eps;
    float et  = eps * om;
    float e2  = eps * eps;
    float beta  = sk + (dk1 + dk - 2.f*sk) * et;
    float rb    = __builtin_amdgcn_rcpf(beta);
    float alpha = hk * (sk*e2 + dk*et);
    float yv  = msk ? xv : (yk + alpha * rb);
    float num = dk1*e2 + 2.f*sk*et + dk*om*om;
    float arg = sk*sk*num*rb*rb;                // exp(logdet): bounded, no overflow
    float ld  = msk ? 0.f : __logf(arg);

    out[gr*16 + t] = yv;
    ldet[tid] = ld;
  }
  __syncthreads();

  if (tid < 64){
    float s = 0.f;
    #pragma unroll
    for (int t=0;t<8;t++) s += ldet[tid*8 + t];
    out[(long)nrows*16 + row0 + tid] = s;
  }
}

extern "C" void kernel_launch(void* const* d_in, const int* in_sizes, int n_in,
                              void* d_out, int out_size, void* d_ws, size_t ws_size,
                              hipStream_t stream)
{
  const float* x    = (const float*)d_in[0];
  const float* W0   = (const float*)d_in[1];
  const float* b0   = (const float*)d_in[2];
  const float* W1   = (const float*)d_in[3];
  const float* b1   = (const float*)d_in[4];
  const float* Wout = (const float*)d_in[5];
  const float* bout = (const float*)d_in[6];
  float* out = (float*)d_out;
  __bf16* sw = (__bf16*)d_ws;

  int nrows = in_sizes[0] / 16;          // 524288
  int ntiles = nrows / 64;               // 8192

  prep_kernel<<<(SW_TOTAL + 255)/256, 256, 0, stream>>>(W0, W1, Wout, sw);
  fused_kernel<<<ntiles, 512, 0, stream>>>(x, b0, b1, bout, sw, out, nrows);
}

// Round 3
// 265.631 us; speedup vs baseline: 1.5141x; 1.0217x over previous
//
#include <hip/hip_runtime.h>
#include <hip/hip_bf16.h>

// CouplingSplineLayer fused kernel for MI355X (gfx950), round 3.
// GEMM1(8->256)+relu -> GEMM2(256->256)+relu -> GEMM3(256->184) -> RQ spline.
// R3: GEMM1/2 computed TRANSPOSED (h^T = W^T @ x^T). Because the MFMA C/D
// layout gives each lane 4 consecutive rows (= hidden dim when transposed),
// C-writes become packed ds_write_b64 into h[batch][hidden] — the exact same
// layout GEMM(k+1) reads as b128 B-frags (A/B frag layouts are symmetric).
// DS-pipe instruction count per block drops ~2.2x vs R2 (the R2 bottleneck).

typedef __bf16 bf16x8 __attribute__((ext_vector_type(8)));
typedef __bf16 bf16x4 __attribute__((ext_vector_type(4)));
typedef float  f32x4  __attribute__((ext_vector_type(4)));

#define MFMA16(a,b,c) __builtin_amdgcn_mfma_f32_16x16x32_bf16((a),(b),(c),0,0,0)

// swizzled weight regions (bf16 element offsets in d_ws); frag layout is the
// same for A-use (transposed GEMMs) and B-use (GEMM3): elem = W[k][n] at
// sw[((kb*NT + tile)*64 + lane)*8 + j], k = kb*32 + (lane>>4)*8 + j, n = tile*16 + (lane&15)
#define SW_W1_OFF 8192      // W0: 1 kb * 16 tiles * 512
#define SW_WO_OFF 73728     // W1: 8 kb * 16 tiles * 512
#define SW_TOTAL  122880    // Wout: 8 kb * 12 tiles * 512

#define HSTRIDE 264         // h row stride in bf16 (528 B: 16B-aligned, 4-bank rot/row)

__global__ void prep_kernel(const float* __restrict__ W0,
                            const float* __restrict__ W1,
                            const float* __restrict__ Wout,
                            __bf16* __restrict__ sw)
{
  int i = blockIdx.x * 256 + threadIdx.x;
  if (i >= SW_TOTAL) return;
  const float* src; int K, N, NT, li;
  if (i < SW_W1_OFF)      { src = W0;   K = 8;   N = 256; NT = 16; li = i; }
  else if (i < SW_WO_OFF) { src = W1;   K = 256; N = 256; NT = 16; li = i - SW_W1_OFF; }
  else                    { src = Wout; K = 256; N = 184; NT = 12; li = i - SW_WO_OFF; }
  int j    = li & 7;
  int l    = (li >> 3) & 63;
  int rest = li >> 9;
  int nt   = rest % NT;
  int kb   = rest / NT;
  int k = kb * 32 + ((l >> 4) << 3) + j;
  int n = nt * 16 + (l & 15);
  float v = (k < K && n < N) ? src[k * N + n] : 0.0f;
  sw[i] = (__bf16)v;
}

__global__ __launch_bounds__(512, 4)
void fused_kernel(const float* __restrict__ x,
                  const float* __restrict__ b0v,
                  const float* __restrict__ b1v,
                  const float* __restrict__ boutv,
                  const __bf16* __restrict__ sw,
                  float* __restrict__ out,
                  int nrows)
{
  // [0, 33792)      h1 (64 x HSTRIDE bf16), later aliased by raw (64 x HSTRIDE)
  // [33792, 67584)  h2 (64 x HSTRIDE bf16), later aliased by ldet (512 f32)
  __shared__ __align__(16) unsigned char smem[2 * 64 * HSTRIDE * 2];
  __bf16* h1   = (__bf16*)smem;
  __bf16* h2   = (__bf16*)(smem + 64 * HSTRIDE * 2);
  __bf16* rawb = h1;
  float*  ldet = (float*)h2;

  const int tid  = threadIdx.x;
  const int wave = tid >> 6;
  const int lane = tid & 63;
  const int quad = lane >> 4;
  const int l16  = lane & 15;
  const int row0 = blockIdx.x * 64;

  const __bf16* swW1 = sw + SW_W1_OFF;
  const __bf16* swWo = sw + SW_WO_OFF;
  const f32x4 z4 = {0.f, 0.f, 0.f, 0.f};

  const int mq = wave >> 1;   // m-quarter (4 mt each) for G1/G2
  const int nh = wave & 1;    // batch-tile pair for G1/G2

  // ---- GEMM1 (transposed): h1[b][m] = relu(sum_k W0[k][m]*x2[b][k] + b0[m])
  {
    bf16x8 bfr[2];
    #pragma unroll
    for (int nt = 0; nt < 2; nt++){
      bf16x8 b = {};                       // k = quad*8+j; only quad 0 (k<8) real,
      if (quad == 0){                      // W0 frags zero-padded past k=8
        const float* xp = x + (long)(row0 + (nh*2 + nt)*16 + l16)*16 + 8;
        float4 u = *(const float4*)xp;
        float4 v = *(const float4*)(xp + 4);
        b[0]=(__bf16)u.x; b[1]=(__bf16)u.y; b[2]=(__bf16)u.z; b[3]=(__bf16)u.w;
        b[4]=(__bf16)v.x; b[5]=(__bf16)v.y; b[6]=(__bf16)v.z; b[7]=(__bf16)v.w;
      }
      bfr[nt] = b;
    }
    #pragma unroll
    for (int mi = 0; mi < 4; mi++){
      int mt = mq*4 + mi;
      bf16x8 a = *(const bf16x8*)(sw + (mt*64 + lane)*8);
      f32x4 acc0 = MFMA16(a, bfr[0], z4);
      f32x4 acc1 = MFMA16(a, bfr[1], z4);
      float4 bb = *(const float4*)(b0v + mt*16 + quad*4);   // bias along m
      bf16x4 p0, p1;
      p0[0]=(__bf16)fmaxf(acc0[0]+bb.x,0.f); p0[1]=(__bf16)fmaxf(acc0[1]+bb.y,0.f);
      p0[2]=(__bf16)fmaxf(acc0[2]+bb.z,0.f); p0[3]=(__bf16)fmaxf(acc0[3]+bb.w,0.f);
      p1[0]=(__bf16)fmaxf(acc1[0]+bb.x,0.f); p1[1]=(__bf16)fmaxf(acc1[1]+bb.y,0.f);
      p1[2]=(__bf16)fmaxf(acc1[2]+bb.z,0.f); p1[3]=(__bf16)fmaxf(acc1[3]+bb.w,0.f);
      *(bf16x4*)(h1 + ((nh*2+0)*16 + l16)*HSTRIDE + mt*16 + quad*4) = p0;
      *(bf16x4*)(h1 + ((nh*2+1)*16 + l16)*HSTRIDE + mt*16 + quad*4) = p1;
    }
  }
  __syncthreads();

  // ---- GEMM2 (transposed): h2[b][m] = relu(sum_k W1[k][m]*h1[b][k] + b1[m])
  {
    f32x4 acc[4][2];
    #pragma unroll
    for (int mi=0;mi<4;mi++){ acc[mi][0]=z4; acc[mi][1]=z4; }
    #pragma unroll
    for (int kb=0;kb<8;kb++){
      bf16x8 bfr[2];
      #pragma unroll
      for (int nt=0;nt<2;nt++)
        bfr[nt] = *(const bf16x8*)(h1 + ((nh*2+nt)*16 + l16)*HSTRIDE + kb*32 + quad*8);
      #pragma unroll
      for (int mi=0;mi<4;mi++){
        bf16x8 a = *(const bf16x8*)(swW1 + ((kb*16 + mq*4 + mi)*64 + lane)*8);
        acc[mi][0] = MFMA16(a, bfr[0], acc[mi][0]);
        acc[mi][1] = MFMA16(a, bfr[1], acc[mi][1]);
      }
    }
    #pragma unroll
    for (int mi=0;mi<4;mi++){
      int mt = mq*4 + mi;
      float4 bb = *(const float4*)(b1v + mt*16 + quad*4);
      #pragma unroll
      for (int nt=0;nt<2;nt++){
        bf16x4 p;
        p[0]=(__bf16)fmaxf(acc[mi][nt][0]+bb.x,0.f);
        p[1]=(__bf16)fmaxf(acc[mi][nt][1]+bb.y,0.f);
        p[2]=(__bf16)fmaxf(acc[mi][nt][2]+bb.z,0.f);
        p[3]=(__bf16)fmaxf(acc[mi][nt][3]+bb.w,0.f);
        *(bf16x4*)(h2 + ((nh*2+nt)*16 + l16)*HSTRIDE + mt*16 + quad*4) = p;
      }
    }
  }
  __syncthreads();

  // ---- GEMM3 (original): raw[b][n] = h2[b][:] @ Wout[:][n] + bout[n]
  {
    const int mh = wave >> 2;          // batch-half (2 mt each)
    const int nc = wave & 3;           // 3 n-tiles each
    f32x4 acc[2][3];
    #pragma unroll
    for (int mi=0;mi<2;mi++)
      #pragma unroll
      for (int ni=0;ni<3;ni++) acc[mi][ni] = z4;
    #pragma unroll
    for (int kb=0;kb<8;kb++){
      bf16x8 af[2];
      #pragma unroll
      for (int mi=0;mi<2;mi++)
        af[mi] = *(const bf16x8*)(h2 + ((mh*2+mi)*16 + l16)*HSTRIDE + kb*32 + quad*8);
      #pragma unroll
      for (int ni=0;ni<3;ni++){
        bf16x8 b = *(const bf16x8*)(swWo + ((kb*12 + nc*3 + ni)*64 + lane)*8);
        acc[0][ni] = MFMA16(af[0], b, acc[0][ni]);
        acc[1][ni] = MFMA16(af[1], b, acc[1][ni]);
      }
    }
    #pragma unroll
    for (int ni=0;ni<3;ni++){
      int col = (nc*3 + ni)*16 + l16;
      if (col < 184){
        int t = (col * 713) >> 14;     // col / 23
        float bias = boutv[col];
        #pragma unroll
        for (int mi=0;mi<2;mi++)
          #pragma unroll
          for (int r=0;r<4;r++){
            int row = (mh*2+mi)*16 + quad*4 + r;
            rawb[row*HSTRIDE + col + t] = (__bf16)(acc[mi][ni][r] + bias);
          }
      }
    }
  }
  __syncthreads();

  // ---- RQ spline epilogue: 512 tasks, 1/thread, scratch-free
  {
    int row = tid >> 3;
    int t   = tid & 7;
    long gr = row0 + row;
    float xv = x[gr*16 + t];
    out[gr*16 + 8 + t] = x[gr*16 + 8 + t];      // x2 passthrough

    const __bf16* rr = rawb + row*HSTRIDE + t*24;   // 48B slots: b128-aligned
    bf16x8 v0 = *(const bf16x8*)(rr);
    bf16x8 v1 = *(const bf16x8*)(rr + 8);
    bf16x8 v2 = *(const bf16x8*)(rr + 16);

    float ew[8], eh[8];
    float sw_ = 0.f, sh_ = 0.f;
    #pragma unroll
    for (int i=0;i<8;i++){ ew[i] = __expf((float)v0[i]); sw_ += ew[i]; }
    #pragma unroll
    for (int i=0;i<8;i++){ eh[i] = __expf((float)v1[i]); sh_ += eh[i]; }
    float cw = 1.9984f * __builtin_amdgcn_rcpf(sw_);
    float ch = 1.9984f * __builtin_amdgcn_rcpf(sh_);

    float d[9];
    d[0] = 1.f; d[8] = 1.f;
    #pragma unroll
    for (int i=0;i<7;i++){
      float z = (float)v2[i] + 0.54116666f;     // log(exp(1-MIN_D)-1)
      d[i+1] = fmaxf(z, 0.f) + __logf(1.f + __expf(-fabsf(z))) + 1e-4f;
    }

    bool msk = (xv <= -0.999f) || (xv >= 0.999f);
    float xin = msk ? 0.f : xv;

    float w_i = fmaf(ew[0], cw, 2e-4f);
    float h_i = fmaf(eh[0], ch, 2e-4f);
    float edge = -1.f + w_i, cy = -1.f + h_i;
    float xk = -1.f, yk = -1.f, wk = w_i, hk = h_i, dk = d[0], dk1 = d[1];
    #pragma unroll
    for (int i=1;i<8;i++){
      w_i = fmaf(ew[i], cw, 2e-4f);
      h_i = fmaf(eh[i], ch, 2e-4f);
      bool le = (edge <= xin);
      xk  = le ? edge : xk;
      yk  = le ? cy   : yk;
      wk  = le ? w_i  : wk;
      hk  = le ? h_i  : hk;
      dk  = le ? d[i] : dk;
      dk1 = le ? d[i+1] : dk1;
      edge += w_i; cy += h_i;
    }

    float rwk = __builtin_amdgcn_rcpf(wk);
    float sk  = hk * rwk;
    float eps = (xin - xk) * rwk;
    float om  = 1.f - eps;
    float et  = eps * om;
    float e2  = eps * eps;
    float beta  = sk + (dk1 + dk - 2.f*sk) * et;
    float rb    = __builtin_amdgcn_rcpf(beta);
    float alpha = hk * (sk*e2 + dk*et);
    float yv  = msk ? xv : (yk + alpha * rb);
    float num = dk1*e2 + 2.f*sk*et + dk*om*om;
    float arg = sk*sk*num*rb*rb;
    float ld  = msk ? 0.f : __logf(arg);

    out[gr*16 + t] = yv;
    ldet[tid] = ld;
  }
  __syncthreads();

  if (tid < 64){
    float s = 0.f;
    #pragma unroll
    for (int t=0;t<8;t++) s += ldet[tid*8 + t];
    out[(long)nrows*16 + row0 + tid] = s;
  }
}

extern "C" void kernel_launch(void* const* d_in, const int* in_sizes, int n_in,
                              void* d_out, int out_size, void* d_ws, size_t ws_size,
                              hipStream_t stream)
{
  const float* x    = (const float*)d_in[0];
  const float* W0   = (const float*)d_in[1];
  const float* b0   = (const float*)d_in[2];
  const float* W1   = (const float*)d_in[3];
  const float* b1   = (const float*)d_in[4];
  const float* Wout = (const float*)d_in[5];
  const float* bout = (const float*)d_in[6];
  float* out = (float*)d_out;
  __bf16* sw = (__bf16*)d_ws;

  int nrows = in_sizes[0] / 16;          // 524288
  int ntiles = nrows / 64;               // 8192

  prep_kernel<<<(SW_TOTAL + 255)/256, 256, 0, stream>>>(W0, W1, Wout, sw);
  fused_kernel<<<ntiles, 512, 0, stream>>>(x, b0, b1, bout, sw, out, nrows);
}